// Round 1
// baseline (3296.678 us; speedup 1.0000x reference)
//
#include <hip/hip_runtime.h>

// LSTMencoder: 2-layer biLSTM, B=256, T=2048, H=32 (4H=128 gates), in=32/64.
// Strategy: 512 independent recurrence chains (batch x dir), one wave per
// chain, persistent over T. h broadcast via readlane->SGPR; input GEMM on the
// fly via broadcast loads (no xg workspace). ws holds only h1 [T,B,64] f32.

#define T_LEN 2048
#define BATCH 256
#define HID   32

__device__ __forceinline__ float frcp(float x) { return __builtin_amdgcn_rcpf(x); }
__device__ __forceinline__ float rdlane(float v, int k) {
    return __int_as_float(__builtin_amdgcn_readlane(__float_as_int(v), k));
}

template<int N>
__device__ __forceinline__ void load_row(float* dst, const float* __restrict__ src) {
#pragma unroll
    for (int i = 0; i < N / 4; ++i) {
        float4 v = reinterpret_cast<const float4*>(src)[i];
        dst[4*i+0] = v.x; dst[4*i+1] = v.y; dst[4*i+2] = v.z; dst[4*i+3] = v.w;
    }
}

// LAYER 0: x[t] = concat(OS[b][t][0:16], IS[b][T-1-t][0:16]); writes h1[t][b][dir*32+j]
// LAYER 1: x[t] = h1[t][b][0:64];                              writes out[b][t][dir*32+j]
template<int LAYER>
__global__ __launch_bounds__(64, 1) void lstm_rec(
        const float* __restrict__ OS, const float* __restrict__ IS,
        const float* __restrict__ Wih, const float* __restrict__ Whh,
        const float* __restrict__ bih, const float* __restrict__ bhh,
        const float* __restrict__ h1in, float* __restrict__ outp)
{
    constexpr int F = (LAYER == 0) ? 32 : 64;
    const int l   = threadIdx.x;     // 0..63
    const int b   = blockIdx.x;      // 0..255
    const int dir = blockIdx.y;      // 0 fwd, 1 bwd
    const int gA  = l;               // i (l<32) or f (l>=32)  -- PyTorch gate order i,f,g,o
    const int gB  = 64 + l;          // g (l<32) or o (l>=32)

    // Per-lane weight rows in VGPRs (loaded once).
    float wih_a[F], wih_b[F], whh_a[HID], whh_b[HID];
    load_row<F>(wih_a, Wih + ((size_t)dir * 128 + gA) * F);
    load_row<F>(wih_b, Wih + ((size_t)dir * 128 + gB) * F);
    load_row<HID>(whh_a, Whh + ((size_t)dir * 128 + gA) * HID);
    load_row<HID>(whh_b, Whh + ((size_t)dir * 128 + gB) * HID);
    const float biasA = bih[dir * 128 + gA] + bhh[dir * 128 + gA];
    const float biasB = bih[dir * 128 + gB] + bhh[dir * 128 + gB];

    float h[HID];                    // wave-uniform copy of h (readlane -> SGPR)
#pragma unroll
    for (int k = 0; k < HID; ++k) h[k] = 0.f;
    float c = 0.f;                   // lane j<32 owns c[j]
    const bool lo = (l < HID);

    float4 X0[F / 4], X1[F / 4];     // broadcast x double-buffer

    auto load_x = [&](float4* X, int tl) {
        const int te = dir ? (T_LEN - 1 - tl) : tl;
        if constexpr (LAYER == 0) {
            const float4* p0 = reinterpret_cast<const float4*>(OS + ((size_t)b * T_LEN + te) * 16);
            const float4* p1 = reinterpret_cast<const float4*>(IS + ((size_t)b * T_LEN + (T_LEN - 1 - te)) * 16);
#pragma unroll
            for (int i = 0; i < 4; ++i) X[i] = p0[i];
#pragma unroll
            for (int i = 0; i < 4; ++i) X[4 + i] = p1[i];
        } else {
            const float4* p = reinterpret_cast<const float4*>(h1in + ((size_t)te * BATCH + b) * 64);
#pragma unroll
            for (int i = 0; i < F / 4; ++i) X[i] = p[i];
        }
    };

    auto step = [&](int tl, const float4* X) {
        const int te = dir ? (T_LEN - 1 - tl) : tl;
        float accA = biasA, accB = biasB;
        // input-side dot (x broadcast in VGPRs, W per-lane)
#pragma unroll
        for (int i = 0; i < F / 4; ++i) {
            accA = fmaf(X[i].x, wih_a[4*i+0], accA);
            accA = fmaf(X[i].y, wih_a[4*i+1], accA);
            accA = fmaf(X[i].z, wih_a[4*i+2], accA);
            accA = fmaf(X[i].w, wih_a[4*i+3], accA);
            accB = fmaf(X[i].x, wih_b[4*i+0], accB);
            accB = fmaf(X[i].y, wih_b[4*i+1], accB);
            accB = fmaf(X[i].z, wih_b[4*i+2], accB);
            accB = fmaf(X[i].w, wih_b[4*i+3], accB);
        }
        // recurrent dot (h wave-uniform/SGPR, W per-lane)
#pragma unroll
        for (int k = 0; k < HID; ++k) {
            accA = fmaf(h[k], whh_a[k], accA);
            accB = fmaf(h[k], whh_b[k], accB);
        }
        // nonlinearities: accA -> sigmoid (i or f); accB -> tanh (g) or sigmoid (o)
        float sA = frcp(1.f + __expf(-accA));
        float argB = lo ? (-2.f * accB) : (-accB);
        float rB = frcp(1.f + __expf(argB));
        float sB = lo ? fmaf(2.f, rB, -1.f) : rB;
        // lane j<32 fetches sigma(f_j), sigma(o_j) from lane 32+j
        float sf = __shfl(sA, (l + 32) & 63);
        float so = __shfl(sB, (l + 32) & 63);
        // c_j = sig(f)*c + sig(i)*tanh(g);  h_j = sig(o)*tanh(c)   (lanes >=32: benign garbage)
        c = fmaf(sf, c, sA * sB);
        float tc = fmaf(2.f, frcp(1.f + __expf(-2.f * c)), -1.f);
        float hj = so * tc;
        if (lo) {
            if constexpr (LAYER == 0)
                outp[((size_t)te * BATCH + b) * 64 + dir * HID + l] = hj;
            else
                outp[((size_t)b * T_LEN + te) * 64 + dir * HID + l] = hj;
        }
        // broadcast new h to wave-uniform regs (readlane ignores exec; lanes 0..31 valid)
#pragma unroll
        for (int k = 0; k < HID; ++k) h[k] = rdlane(hj, k);
    };

    load_x(X0, 0);
#pragma unroll 1
    for (int tt = 0; tt < T_LEN; tt += 2) {
        load_x(X1, tt + 1);          // prefetch next step
        step(tt, X0);
        int nx = tt + 2; if (nx > T_LEN - 1) nx = T_LEN - 1;
        load_x(X0, nx);              // prefetch step after next (clamped)
        step(tt + 1, X1);
    }
}

extern "C" void kernel_launch(void* const* d_in, const int* in_sizes, int n_in,
                              void* d_out, int out_size, void* d_ws, size_t ws_size,
                              hipStream_t stream) {
    const float* OS    = (const float*)d_in[0];
    const float* IS    = (const float*)d_in[1];
    const float* W_ih0 = (const float*)d_in[2];
    const float* W_hh0 = (const float*)d_in[3];
    const float* b_ih0 = (const float*)d_in[4];
    const float* b_hh0 = (const float*)d_in[5];
    const float* W_ih1 = (const float*)d_in[6];
    const float* W_hh1 = (const float*)d_in[7];
    const float* b_ih1 = (const float*)d_in[8];
    const float* b_hh1 = (const float*)d_in[9];
    float* out = (float*)d_out;
    float* h1  = (float*)d_ws;       // [T, B, 64] f32 = 128 MiB intermediate

    dim3 grid(BATCH, 2), block(64);
    hipLaunchKernelGGL((lstm_rec<0>), grid, block, 0, stream,
                       OS, IS, W_ih0, W_hh0, b_ih0, b_hh0, (const float*)nullptr, h1);
    hipLaunchKernelGGL((lstm_rec<1>), grid, block, 0, stream,
                       (const float*)nullptr, (const float*)nullptr,
                       W_ih1, W_hh1, b_ih1, b_hh1, (const float*)h1, out);
}